// Round 1
// baseline (713.062 us; speedup 1.0000x reference)
//
#include <hip/hip_runtime.h>
#include <math.h>

#define NC 25
#define NHID 50
#define NB 32
#define NH 256
#define NW 256
#define NOH 252
#define NOW 252

#define CHUNK 28          // output rows per block
#define NCHUNK 9          // 9*28 = 252
#define INROWS 34         // CHUNK + 6 input rows (iy = r0-1 .. r0+32)

// ---------------------------------------------------------------------------
// Exact-accuracy GELU via Abramowitz-Stegun 7.1.26 erf (|err| <= 1.5e-7).
// Branchless: 1 v_rcp_f32 + 1 v_exp_f32 + ~12 FMAs, vs libm erff's ~40-50
// divergent instructions.
// ---------------------------------------------------------------------------
__device__ __forceinline__ float gelu_exact(float h)
{
    const float x  = h * 0.70710678118654752f;   // h / sqrt(2)
    const float ax = fabsf(x);
    const float t  = __builtin_amdgcn_rcpf(fmaf(0.3275911f, ax, 1.0f));
    float p = fmaf(1.061405429f, t, -1.453152027f);
    p = fmaf(p, t, 1.421413741f);
    p = fmaf(p, t, -0.284496736f);
    p = fmaf(p, t, 0.254829592f);
    p = p * t;
    const float e  = __builtin_amdgcn_exp2f(ax * ax * -1.4426950408889634f);
    float er = fmaf(-p, e, 1.0f);                // erf(|x|)
    er = copysignf(er, x);
    return 0.5f * h * (1.0f + er);
}

// ---------------------------------------------------------------------------
// conv pass: NR consecutive output rows starting at ring-local row lbase.
// Lane L covers output cols 4L..4L+3; needs ring cols [4L+3 .. 4L+12].
// Loaded as 4 aligned float4 (cols 4L..4L+15): contiguous b128 across lanes
// is bank-conflict-free (the old rp[3]/rp[12] scalars were 8-way conflicts).
// ---------------------------------------------------------------------------
template<int NR>
__device__ __forceinline__ void conv_pass7(
    const float (*ring)[264], const float* wgt, int lbase, int lane,
    float (*acc)[4])
{
#pragma unroll
    for (int r = 0; r < NR + 6; ++r) {
        const float* rp = &ring[lbase + r][4 * lane];
        const float4 q0 = *(const float4*)(rp);
        const float4 q1 = *(const float4*)(rp + 4);
        const float4 q2 = *(const float4*)(rp + 8);
        const float4 q3 = *(const float4*)(rp + 12);
        float xv[10];
        xv[0] = q0.w;
        xv[1] = q1.x; xv[2] = q1.y; xv[3] = q1.z; xv[4] = q1.w;
        xv[5] = q2.x; xv[6] = q2.y; xv[7] = q2.z; xv[8] = q2.w;
        xv[9] = q3.x;
#pragma unroll
        for (int j = 0; j < NR; ++j) {
            const int ky = r - j;
            if (ky >= 0 && ky < 7) {
#pragma unroll
                for (int cc = 0; cc < 4; ++cc) {
#pragma unroll
                    for (int kx = 0; kx < 7; ++kx)
                        acc[j][cc] = fmaf(wgt[ky * 7 + kx], xv[cc + kx], acc[j][cc]);
                }
            }
        }
    }
}

// ---------------------------------------------------------------------------
// Kernel 1: one block per (plane, chunk). Computes partial 9-stats of
// g = gelu(conv7(x)+bias) over output rows [chunk*28, chunk*28+28).
// stats: T, R0, R251, C0, C251, g00, g0R, gR0, gRR  (zero where not in chunk)
// ---------------------------------------------------------------------------
__global__ __launch_bounds__(256, 4) void stats_kernel(
    const float* __restrict__ x, const float* __restrict__ w7,
    const float* __restrict__ b7, float* __restrict__ partial)
{
    const int bid   = blockIdx.x;       // plane*NCHUNK + chunk
    const int plane = bid / NCHUNK;
    const int chunk = bid - plane * NCHUNK;
    const int c     = plane % NC;
    const int r0    = chunk * CHUNK;
    const float* xp = x + (size_t)plane * (NH * NW);

    float wgt[49];
#pragma unroll
    for (int i = 0; i < 49; ++i) wgt[i] = w7[c * 49 + i];
    const float bias = b7[c];

    __shared__ __attribute__((aligned(16))) float ring[INROWS][264];
    __shared__ float red[4][9];

    const int tid  = threadIdx.x;
    const int wave = tid >> 6;
    const int lane = tid & 63;

    // ---- stage all INROWS input rows, float4 per thread, one barrier ----
    // ring col l <-> input col l-4. part p writes ring cols [4p,4p+4) i.e.
    // input cols [4p-4, 4p): p in [1,64] are interior aligned float4 loads.
    for (int idx = tid; idx < INROWS * 66; idx += 256) {
        const int row = idx / 66;
        const int p   = idx - row * 66;
        const int iy  = r0 - 1 + row;
        float4 v = make_float4(0.f, 0.f, 0.f, 0.f);
        if (p >= 1 && p <= 64 && iy >= 0 && iy < NH)
            v = *(const float4*)&xp[iy * NW + 4 * (p - 1)];
        *(float4*)&ring[row][4 * p] = v;
    }
    __syncthreads();

    // ---- compute: wave handles output rows r0 + wave*7 + [0,7), one pass ----
    float tot = 0.f, r0s = 0.f, r251s = 0.f, c0s = 0.f, c251s = 0.f;
    float g00 = 0.f, g0R = 0.f, gR0 = 0.f, gRR = 0.f;

    if (lane < 63) {
        float acc[7][4];
#pragma unroll
        for (int j = 0; j < 7; ++j)
#pragma unroll
            for (int cc = 0; cc < 4; ++cc) acc[j][cc] = 0.f;

        conv_pass7<7>(ring, wgt, wave * 7, lane, acc);

#pragma unroll
        for (int j = 0; j < 7; ++j) {
            const int oy = r0 + wave * 7 + j;
            float g[4];
#pragma unroll
            for (int cc = 0; cc < 4; ++cc)
                g[cc] = gelu_exact(acc[j][cc] + bias);
            const float s4 = (g[0] + g[1]) + (g[2] + g[3]);
            tot += s4;
            if (lane == 0)  c0s   += g[0];
            if (lane == 62) c251s += g[3];
            if (oy == 0)   { r0s   += s4; if (lane == 0) g00 += g[0]; if (lane == 62) g0R += g[3]; }
            if (oy == 251) { r251s += s4; if (lane == 0) gR0 += g[0]; if (lane == 62) gRR += g[3]; }
        }
    }

    // ---- block reduction of the 9 stats ----
    float st[9] = {tot, r0s, r251s, c0s, c251s, g00, g0R, gR0, gRR};
#pragma unroll
    for (int i = 0; i < 9; ++i) {
        float v = st[i];
        for (int off = 32; off > 0; off >>= 1) v += __shfl_down(v, off, 64);
        st[i] = v;
    }
    if (lane == 0) {
#pragma unroll
        for (int i = 0; i < 9; ++i) red[wave][i] = st[i];
    }
    __syncthreads();
    if (tid < 9)
        partial[(size_t)bid * 9 + tid] =
            (red[0][tid] + red[1][tid]) + (red[2][tid] + red[3][tid]);
}

// ---------------------------------------------------------------------------
// Kernel 2: per-batch. Sum chunk partials (fixed order -> deterministic),
// reconstruct conv3 mean via inclusion-exclusion, MLP, sigmoid, rank.
// ---------------------------------------------------------------------------
__global__ __launch_bounds__(64) void mlp_kernel(
    const float* __restrict__ partial, const float* __restrict__ w3,
    const float* __restrict__ fc1w, const float* __restrict__ fc1b,
    const float* __restrict__ fc2w, const float* __restrict__ fc2b,
    float* __restrict__ idx_out, float* __restrict__ gate_ws,
    int* __restrict__ src_ws)
{
    const int b = blockIdx.x;
    const int t = threadIdx.x;
    __shared__ float mean_s[NC], hid_s[NHID], s_s[NC];

    if (t < NC) {
        const float* base = partial + (size_t)(b * NC + t) * NCHUNK * 9;
        double acc[9];
#pragma unroll
        for (int i = 0; i < 9; ++i) acc[i] = 0.0;
        for (int ch = 0; ch < NCHUNK; ++ch)
#pragma unroll
            for (int i = 0; i < 9; ++i) acc[i] += (double)base[ch * 9 + i];

        float T = (float)acc[0], R0 = (float)acc[1], R251 = (float)acc[2];
        float C0 = (float)acc[3], C251 = (float)acc[4];
        float g00 = (float)acc[5], g0R = (float)acc[6];
        float gR0 = (float)acc[7], gRR = (float)acc[8];

        float ER[3] = {R251, 0.f, R0};
        float EC[3] = {C251, 0.f, C0};
        float CR[3][3] = {{gRR, 0.f, gR0}, {0.f, 0.f, 0.f}, {g0R, 0.f, g00}};
        float m = 0.f;
#pragma unroll
        for (int ky = 0; ky < 3; ++ky)
#pragma unroll
            for (int kx = 0; kx < 3; ++kx) {
                float S = T - ER[ky] - EC[kx] + CR[ky][kx];
                m += w3[t * 9 + ky * 3 + kx] * S;
            }
        mean_s[t] = m * (1.0f / (252.0f * 252.0f));
    }
    __syncthreads();
    if (t < NHID) {
        float a = fc1b[t];
#pragma unroll
        for (int cc = 0; cc < NC; ++cc) a += mean_s[cc] * fc1w[t * NC + cc];
        hid_s[t] = fmaxf(a, 0.f);
    }
    __syncthreads();
    if (t < NC) {
        float a = fc2b[t];
#pragma unroll
        for (int j = 0; j < NHID; ++j) a += hid_s[j] * fc2w[t * NHID + j];
        s_s[t] = 1.0f / (1.0f + expf(-a));
    }
    __syncthreads();
    if (t < NC) {
        float s = s_s[t];
        int rank = 0;
        for (int c2 = 0; c2 < NC; ++c2) {
            float s2 = s_s[c2];
            if (s2 > s || (s2 == s && c2 < t)) rank++;
        }
        float gate = (s * s) / (s * s + 1e-8f);
        idx_out[b * NC + rank] = (float)t;
        gate_ws[b * NC + rank] = gate;
        src_ws[b * NC + rank]  = t;
    }
}

// ---------------------------------------------------------------------------
// Kernel 3: gather + scale. 4 segment-blocks per output slot.
// ---------------------------------------------------------------------------
__global__ __launch_bounds__(256) void gather_kernel(
    const float* __restrict__ x, const float* __restrict__ gate_ws,
    const int* __restrict__ src_ws, float* __restrict__ out)
{
    const int bid = blockIdx.x;
    const int seg = bid & 3;
    const int p   = bid >> 2;            // b*25 + j
    const int b   = p / NC;
    const int j   = p - b * NC;
    const int src = src_ws[p];
    const float gate = gate_ws[p];

    const float4* xp = (const float4*)(x + ((size_t)(b * NC + src)) * (NH * NW))
                       + seg * 4096;
    float* dst;
    if (j < 10) dst = out + ((size_t)(b * 10 + j)) * (NH * NW);
    else dst = out + (size_t)NB * 10 * (NH * NW) + ((size_t)(b * 15 + (j - 10))) * (NH * NW);
    float4* dp = (float4*)dst + seg * 4096;

    const int t = threadIdx.x;
#pragma unroll 4
    for (int i = t; i < 4096; i += 256) {
        float4 v = xp[i];
        v.x *= gate; v.y *= gate; v.z *= gate; v.w *= gate;
        dp[i] = v;
    }
}

extern "C" void kernel_launch(void* const* d_in, const int* in_sizes, int n_in,
                              void* d_out, int out_size, void* d_ws, size_t ws_size,
                              hipStream_t stream)
{
    const float* x    = (const float*)d_in[0];
    const float* w7   = (const float*)d_in[1];
    const float* b7   = (const float*)d_in[2];
    const float* w3   = (const float*)d_in[3];
    const float* fc1w = (const float*)d_in[4];
    const float* fc1b = (const float*)d_in[5];
    const float* fc2w = (const float*)d_in[6];
    const float* fc2b = (const float*)d_in[7];
    float* out = (float*)d_out;

    float* partial = (float*)d_ws;                        // 800*9*9 floats
    float* gate_ws = partial + NB * NC * NCHUNK * 9;      // 800 floats
    int*   src_ws  = (int*)(gate_ws + NB * NC);           // 800 ints

    float* idx_out = out + (size_t)NB * 10 * (NH * NW) + (size_t)NB * 15 * (NH * NW);

    stats_kernel<<<NB * NC * NCHUNK, 256, 0, stream>>>(x, w7, b7, partial);
    mlp_kernel<<<NB, 64, 0, stream>>>(partial, w3, fc1w, fc1b, fc2w, fc2b,
                                      idx_out, gate_ws, src_ws);
    gather_kernel<<<NB * NC * 4, 256, 0, stream>>>(x, gate_ws, src_ws, out);
}

// Round 2
// 547.072 us; speedup vs baseline: 1.3034x; 1.3034x over previous
//
#include <hip/hip_runtime.h>
#include <math.h>

#define NC 25
#define NHID 50
#define NB 32
#define NH 256
#define NW 256
#define NOH 252
#define NOW 252

#define CHUNK 28          // output rows per block
#define NCHUNK 9          // 9*28 = 252
#define INROWS 34         // CHUNK + 6 input rows (iy = r0-1 .. r0+32)

// ---------------------------------------------------------------------------
// Exact-accuracy GELU via Abramowitz-Stegun 7.1.26 erf (|err| <= 1.5e-7).
// Branchless: 1 v_rcp_f32 + 1 v_exp_f32 + ~12 FMAs, vs libm erff's ~40-50
// divergent instructions.
// ---------------------------------------------------------------------------
__device__ __forceinline__ float gelu_exact(float h)
{
    const float x  = h * 0.70710678118654752f;   // h / sqrt(2)
    const float ax = fabsf(x);
    const float t  = __builtin_amdgcn_rcpf(fmaf(0.3275911f, ax, 1.0f));
    float p = fmaf(1.061405429f, t, -1.453152027f);
    p = fmaf(p, t, 1.421413741f);
    p = fmaf(p, t, -0.284496736f);
    p = fmaf(p, t, 0.254829592f);
    p = p * t;
    const float e  = __builtin_amdgcn_exp2f(ax * ax * -1.4426950408889634f);
    float er = fmaf(-p, e, 1.0f);                // erf(|x|)
    er = copysignf(er, x);
    return 0.5f * h * (1.0f + er);
}

// ---------------------------------------------------------------------------
// conv pass: NR consecutive output rows starting at ring-local row lbase.
// Lane L covers output cols 4L..4L+3; needs ring cols [4L+3 .. 4L+12].
// Middle 8 cols = two FULLY-USED ds_read_b128 (conflict-free, can't be
// narrowed by DCE). Edge cols come from neighbor lanes via shuffle:
//   col 4L+3  = lane L-1's q1.w   (lane 0: ring col 3 = zero-pad)
//   col 4L+12 = lane L+1's q2.x   (lane 63 inactive in stats; its own loads
//                                  read ring cols 256..263, staged zeros)
// ALL 64 lanes must execute this (shuffle sources), stats masked later.
// ---------------------------------------------------------------------------
template<int NR>
__device__ __forceinline__ void conv_pass7(
    const float (*ring)[264], const float* wgt, int lbase, int lane,
    float (*acc)[4])
{
#pragma unroll
    for (int r = 0; r < NR + 6; ++r) {
        const float* rp = &ring[lbase + r][4 * lane];
        const float4 q1 = *(const float4*)(rp + 4);
        const float4 q2 = *(const float4*)(rp + 8);
        float xv0 = __shfl_up(q1.w, 1, 64);
        if (lane == 0) xv0 = 0.f;                // padded input col -1
        const float xv9 = __shfl_down(q2.x, 1, 64);
        float xv[10];
        xv[0] = xv0;
        xv[1] = q1.x; xv[2] = q1.y; xv[3] = q1.z; xv[4] = q1.w;
        xv[5] = q2.x; xv[6] = q2.y; xv[7] = q2.z; xv[8] = q2.w;
        xv[9] = xv9;
#pragma unroll
        for (int j = 0; j < NR; ++j) {
            const int ky = r - j;
            if (ky >= 0 && ky < 7) {
#pragma unroll
                for (int cc = 0; cc < 4; ++cc) {
#pragma unroll
                    for (int kx = 0; kx < 7; ++kx)
                        acc[j][cc] = fmaf(wgt[ky * 7 + kx], xv[cc + kx], acc[j][cc]);
                }
            }
        }
    }
}

// ---------------------------------------------------------------------------
// Kernel 1: one block per (plane, chunk). Computes partial 9-stats of
// g = gelu(conv7(x)+bias) over output rows [chunk*28, chunk*28+28).
// stats: T, R0, R251, C0, C251, g00, g0R, gR0, gRR  (zero where not in chunk)
// ---------------------------------------------------------------------------
__global__ __launch_bounds__(256) void stats_kernel(
    const float* __restrict__ x, const float* __restrict__ w7,
    const float* __restrict__ b7, float* __restrict__ partial)
{
    const int bid   = blockIdx.x;       // plane*NCHUNK + chunk
    const int plane = bid / NCHUNK;
    const int chunk = bid - plane * NCHUNK;
    const int c     = plane % NC;
    const int r0    = chunk * CHUNK;
    const float* xp = x + (size_t)plane * (NH * NW);

    float wgt[49];
#pragma unroll
    for (int i = 0; i < 49; ++i) wgt[i] = w7[c * 49 + i];
    const float bias = b7[c];

    __shared__ __attribute__((aligned(16))) float ring[INROWS][264];
    __shared__ float red[4][9];

    const int tid  = threadIdx.x;
    const int wave = tid >> 6;
    const int lane = tid & 63;

    // ---- stage all INROWS input rows, float4 per thread, one barrier ----
    // ring col l <-> input col l-4. part p writes ring cols [4p,4p+4) i.e.
    // input cols [4p-4, 4p): p in [1,64] are interior aligned float4 loads.
    for (int idx = tid; idx < INROWS * 66; idx += 256) {
        const int row = idx / 66;
        const int p   = idx - row * 66;
        const int iy  = r0 - 1 + row;
        float4 v = make_float4(0.f, 0.f, 0.f, 0.f);
        if (p >= 1 && p <= 64 && iy >= 0 && iy < NH)
            v = *(const float4*)&xp[iy * NW + 4 * (p - 1)];
        *(float4*)&ring[row][4 * p] = v;
    }
    __syncthreads();

    // ---- compute: wave handles output rows r0 + wave*7 + [0,7) ----
    float tot = 0.f, r0s = 0.f, r251s = 0.f, c0s = 0.f, c251s = 0.f;
    float g00 = 0.f, g0R = 0.f, gR0 = 0.f, gRR = 0.f;

    const int oyF0 = r0 + wave * 7;            // pass A: rows oyF0..+3
    const int oyF1 = oyF0 + 4;                 // pass B: rows oyF1..+2

    // pass A (4 rows) — conv runs on ALL lanes (shuffle sources), stats masked
    {
        float acc[4][4];
#pragma unroll
        for (int j = 0; j < 4; ++j)
#pragma unroll
            for (int cc = 0; cc < 4; ++cc) acc[j][cc] = 0.f;
        conv_pass7<4>(ring, wgt, oyF0 - r0, lane, acc);
        if (lane < 63) {
#pragma unroll
            for (int j = 0; j < 4; ++j) {
                const int oy = oyF0 + j;
                float g[4];
#pragma unroll
                for (int cc = 0; cc < 4; ++cc)
                    g[cc] = gelu_exact(acc[j][cc] + bias);
                const float s4 = (g[0] + g[1]) + (g[2] + g[3]);
                tot += s4;
                if (lane == 0)  c0s   += g[0];
                if (lane == 62) c251s += g[3];
                if (oy == 0)   { r0s   += s4; if (lane == 0) g00 += g[0]; if (lane == 62) g0R += g[3]; }
                if (oy == 251) { r251s += s4; if (lane == 0) gR0 += g[0]; if (lane == 62) gRR += g[3]; }
            }
        }
    }
    // pass B (3 rows)
    {
        float acc[3][4];
#pragma unroll
        for (int j = 0; j < 3; ++j)
#pragma unroll
            for (int cc = 0; cc < 4; ++cc) acc[j][cc] = 0.f;
        conv_pass7<3>(ring, wgt, oyF1 - r0, lane, acc);
        if (lane < 63) {
#pragma unroll
            for (int j = 0; j < 3; ++j) {
                const int oy = oyF1 + j;
                float g[4];
#pragma unroll
                for (int cc = 0; cc < 4; ++cc)
                    g[cc] = gelu_exact(acc[j][cc] + bias);
                const float s4 = (g[0] + g[1]) + (g[2] + g[3]);
                tot += s4;
                if (lane == 0)  c0s   += g[0];
                if (lane == 62) c251s += g[3];
                if (oy == 0)   { r0s   += s4; if (lane == 0) g00 += g[0]; if (lane == 62) g0R += g[3]; }
                if (oy == 251) { r251s += s4; if (lane == 0) gR0 += g[0]; if (lane == 62) gRR += g[3]; }
            }
        }
    }

    // ---- block reduction of the 9 stats ----
    float st[9] = {tot, r0s, r251s, c0s, c251s, g00, g0R, gR0, gRR};
#pragma unroll
    for (int i = 0; i < 9; ++i) {
        float v = st[i];
        for (int off = 32; off > 0; off >>= 1) v += __shfl_down(v, off, 64);
        st[i] = v;
    }
    if (lane == 0) {
#pragma unroll
        for (int i = 0; i < 9; ++i) red[wave][i] = st[i];
    }
    __syncthreads();
    if (tid < 9)
        partial[(size_t)bid * 9 + tid] =
            (red[0][tid] + red[1][tid]) + (red[2][tid] + red[3][tid]);
}

// ---------------------------------------------------------------------------
// Kernel 2: per-batch. Sum chunk partials (fixed order -> deterministic),
// reconstruct conv3 mean via inclusion-exclusion, MLP, sigmoid, rank.
// ---------------------------------------------------------------------------
__global__ __launch_bounds__(64) void mlp_kernel(
    const float* __restrict__ partial, const float* __restrict__ w3,
    const float* __restrict__ fc1w, const float* __restrict__ fc1b,
    const float* __restrict__ fc2w, const float* __restrict__ fc2b,
    float* __restrict__ idx_out, float* __restrict__ gate_ws,
    int* __restrict__ src_ws)
{
    const int b = blockIdx.x;
    const int t = threadIdx.x;
    __shared__ float mean_s[NC], hid_s[NHID], s_s[NC];

    if (t < NC) {
        const float* base = partial + (size_t)(b * NC + t) * NCHUNK * 9;
        double acc[9];
#pragma unroll
        for (int i = 0; i < 9; ++i) acc[i] = 0.0;
        for (int ch = 0; ch < NCHUNK; ++ch)
#pragma unroll
            for (int i = 0; i < 9; ++i) acc[i] += (double)base[ch * 9 + i];

        float T = (float)acc[0], R0 = (float)acc[1], R251 = (float)acc[2];
        float C0 = (float)acc[3], C251 = (float)acc[4];
        float g00 = (float)acc[5], g0R = (float)acc[6];
        float gR0 = (float)acc[7], gRR = (float)acc[8];

        float ER[3] = {R251, 0.f, R0};
        float EC[3] = {C251, 0.f, C0};
        float CR[3][3] = {{gRR, 0.f, gR0}, {0.f, 0.f, 0.f}, {g0R, 0.f, g00}};
        float m = 0.f;
#pragma unroll
        for (int ky = 0; ky < 3; ++ky)
#pragma unroll
            for (int kx = 0; kx < 3; ++kx) {
                float S = T - ER[ky] - EC[kx] + CR[ky][kx];
                m += w3[t * 9 + ky * 3 + kx] * S;
            }
        mean_s[t] = m * (1.0f / (252.0f * 252.0f));
    }
    __syncthreads();
    if (t < NHID) {
        float a = fc1b[t];
#pragma unroll
        for (int cc = 0; cc < NC; ++cc) a += mean_s[cc] * fc1w[t * NC + cc];
        hid_s[t] = fmaxf(a, 0.f);
    }
    __syncthreads();
    if (t < NC) {
        float a = fc2b[t];
#pragma unroll
        for (int j = 0; j < NHID; ++j) a += hid_s[j] * fc2w[t * NHID + j];
        s_s[t] = 1.0f / (1.0f + expf(-a));
    }
    __syncthreads();
    if (t < NC) {
        float s = s_s[t];
        int rank = 0;
        for (int c2 = 0; c2 < NC; ++c2) {
            float s2 = s_s[c2];
            if (s2 > s || (s2 == s && c2 < t)) rank++;
        }
        float gate = (s * s) / (s * s + 1e-8f);
        idx_out[b * NC + rank] = (float)t;
        gate_ws[b * NC + rank] = gate;
        src_ws[b * NC + rank]  = t;
    }
}

// ---------------------------------------------------------------------------
// Kernel 3: gather + scale. 4 segment-blocks per output slot.
// ---------------------------------------------------------------------------
__global__ __launch_bounds__(256) void gather_kernel(
    const float* __restrict__ x, const float* __restrict__ gate_ws,
    const int* __restrict__ src_ws, float* __restrict__ out)
{
    const int bid = blockIdx.x;
    const int seg = bid & 3;
    const int p   = bid >> 2;            // b*25 + j
    const int b   = p / NC;
    const int j   = p - b * NC;
    const int src = src_ws[p];
    const float gate = gate_ws[p];

    const float4* xp = (const float4*)(x + ((size_t)(b * NC + src)) * (NH * NW))
                       + seg * 4096;
    float* dst;
    if (j < 10) dst = out + ((size_t)(b * 10 + j)) * (NH * NW);
    else dst = out + (size_t)NB * 10 * (NH * NW) + ((size_t)(b * 15 + (j - 10))) * (NH * NW);
    float4* dp = (float4*)dst + seg * 4096;

    const int t = threadIdx.x;
#pragma unroll 4
    for (int i = t; i < 4096; i += 256) {
        float4 v = xp[i];
        v.x *= gate; v.y *= gate; v.z *= gate; v.w *= gate;
        dp[i] = v;
    }
}

extern "C" void kernel_launch(void* const* d_in, const int* in_sizes, int n_in,
                              void* d_out, int out_size, void* d_ws, size_t ws_size,
                              hipStream_t stream)
{
    const float* x    = (const float*)d_in[0];
    const float* w7   = (const float*)d_in[1];
    const float* b7   = (const float*)d_in[2];
    const float* w3   = (const float*)d_in[3];
    const float* fc1w = (const float*)d_in[4];
    const float* fc1b = (const float*)d_in[5];
    const float* fc2w = (const float*)d_in[6];
    const float* fc2b = (const float*)d_in[7];
    float* out = (float*)d_out;

    float* partial = (float*)d_ws;                        // 800*9*9 floats
    float* gate_ws = partial + NB * NC * NCHUNK * 9;      // 800 floats
    int*   src_ws  = (int*)(gate_ws + NB * NC);           // 800 ints

    float* idx_out = out + (size_t)NB * 10 * (NH * NW) + (size_t)NB * 15 * (NH * NW);

    stats_kernel<<<NB * NC * NCHUNK, 256, 0, stream>>>(x, w7, b7, partial);
    mlp_kernel<<<NB, 64, 0, stream>>>(partial, w3, fc1w, fc1b, fc2w, fc2b,
                                      idx_out, gate_ws, src_ws);
    gather_kernel<<<NB * NC * 4, 256, 0, stream>>>(x, gate_ws, src_ws, out);
}